// Round 10
// baseline (91.438 us; speedup 1.0000x reference)
//
#include <hip/hip_runtime.h>

#define NUM_INPUT   256
#define NUM_OUTPUT  64
#define MAX_DEPTH   10
#define N_INTERNAL  1023

// ---------------- common helpers ----------------

// Sum-reduce across each 16-lane row using DPP row_ror (VALU pipe, no DS ops).
__device__ __forceinline__ float group16_reduce_add(float acc) {
    int t;
    t = __builtin_amdgcn_update_dpp(0, __float_as_int(acc), 0x121, 0xf, 0xf, true);
    acc += __int_as_float(t);
    t = __builtin_amdgcn_update_dpp(0, __float_as_int(acc), 0x122, 0xf, 0xf, true);
    acc += __int_as_float(t);
    t = __builtin_amdgcn_update_dpp(0, __float_as_int(acc), 0x124, 0xf, 0xf, true);
    acc += __int_as_float(t);
    t = __builtin_amdgcn_update_dpp(0, __float_as_int(acc), 0x128, 0xf, 0xf, true);
    acc += __int_as_float(t);
    return acc;
}

// Product-reduce across each 16-lane row.
__device__ __forceinline__ float group16_reduce_mul(float v) {
    int t;
    t = __builtin_amdgcn_update_dpp(0, __float_as_int(v), 0x121, 0xf, 0xf, true);
    v *= __int_as_float(t);
    t = __builtin_amdgcn_update_dpp(0, __float_as_int(v), 0x122, 0xf, 0xf, true);
    v *= __int_as_float(t);
    t = __builtin_amdgcn_update_dpp(0, __float_as_int(v), 0x124, 0xf, 0xf, true);
    v *= __int_as_float(t);
    t = __builtin_amdgcn_update_dpp(0, __float_as_int(v), 0x128, 0xf, 0xf, true);
    v *= __int_as_float(t);
    return v;
}

// 16-lane dot of this group's x fragment with row WPTR (256 floats).
// Fixed FMA order — identical to all passing rounds.
#define DOT16(WPTR, ACC)                                                    \
    {                                                                       \
        const float4* wr_ = reinterpret_cast<const float4*>(WPTR);          \
        float4 w0 = wr_[s], w1 = wr_[16 + s], w2 = wr_[32 + s], w3 = wr_[48 + s]; \
        float a0 = xv0.x * w0.x, a1 = xv1.x * w1.x;                         \
        float a2 = xv2.x * w2.x, a3 = xv3.x * w3.x;                         \
        a0 = fmaf(xv0.y, w0.y, a0); a1 = fmaf(xv1.y, w1.y, a1);             \
        a2 = fmaf(xv2.y, w2.y, a2); a3 = fmaf(xv3.y, w3.y, a3);             \
        a0 = fmaf(xv0.z, w0.z, a0); a1 = fmaf(xv1.z, w1.z, a1);             \
        a2 = fmaf(xv2.z, w2.z, a2); a3 = fmaf(xv3.z, w3.z, a3);             \
        a0 = fmaf(xv0.w, w0.w, a0); a1 = fmaf(xv1.w, w1.w, a1);             \
        a2 = fmaf(xv2.w, w2.w, a2); a3 = fmaf(xv3.w, w3.w, a3);             \
        ACC = group16_reduce_add((a0 + a1) + (a2 + a3));                    \
    }

// One depth step; records -|z| (sigmoid deferred), decision via z>=0.
#define TREE_STEP(WBASE, AARR, BARR, IDX, ZND)                              \
    {                                                                       \
        float a_i = (AARR)[IDX];                                            \
        float b_i = (BARR)[IDX];                                            \
        float acc_;                                                         \
        DOT16((WBASE) + (size_t)(IDX) * NUM_INPUT, acc_);                   \
        float z = a_i * (acc_ + b_i);                                       \
        ZND = __int_as_float(__float_as_int(z) | 0x80000000);               \
        IDX = 2 * (IDX) + 1 + ((z >= 0.0f) ? 1 : 0);                        \
    }

// ---------------- Phase 1: levels 0..4 from LDS, emit idx5/p5 + histogram ----------------
#define P1_THREADS 1024
#define P1_ELEMS   64     // 16 waves * 4 elems

__global__ __launch_bounds__(P1_THREADS) void ogtree_p1(
    const float* __restrict__ x, const float* __restrict__ W,
    const float* __restrict__ b, const float* __restrict__ alpha,
    int* __restrict__ cnt, int* __restrict__ idx5a, float* __restrict__ p5a)
{
    __shared__ float lds_w[31 * NUM_INPUT];   // levels 0..4
    __shared__ float la[31], lb_[31];
    __shared__ int   h[32];

    const int tid  = threadIdx.x;
    const int lane = tid & 63, wid = tid >> 6;
    const int g    = lane >> 4, s = lane & 15;
    const int elem = blockIdx.x * P1_ELEMS + wid * 4 + g;

    // x loads before staging: latency hides under the stage
    const float4* xrow = reinterpret_cast<const float4*>(x + (size_t)elem * NUM_INPUT);
    float4 xv0 = xrow[s], xv1 = xrow[16 + s], xv2 = xrow[32 + s], xv3 = xrow[48 + s];

    {
        const float4* Wv = reinterpret_cast<const float4*>(W);
        float4* lw4 = reinterpret_cast<float4*>(lds_w);
        #pragma unroll
        for (int i = tid; i < 31 * 64; i += P1_THREADS) lw4[i] = Wv[i];
        if (tid < 31) { la[tid] = alpha[tid]; lb_[tid] = b[tid]; }
        if (tid < 32) h[tid] = 0;
    }
    __syncthreads();

    int idx = 0;
    float zn[5];
    #pragma unroll
    for (int d = 0; d < 5; ++d)
        TREE_STEP(lds_w, la, lb_, idx, zn[d]);

    // partial product over levels 0..4: p5 = prod (1 + e^{-|z|})
    float zsel = -1e30f;
    #pragma unroll
    for (int d = 0; d < 5; ++d)
        zsel = (s == d) ? zn[d] : zsel;
    float f = 1.0f + __expf(zsel);           // lanes 5..15 -> 1.0
    float p = group16_reduce_mul(f);

    if (s == 0) {
        idx5a[elem] = idx;                   // level-5 node in [31,62]
        p5a[elem]   = p;
        atomicAdd(&h[idx - 31], 1);
    }
    __syncthreads();
    if (tid < 32 && h[tid] > 0) atomicAdd(&cnt[tid], h[tid]);
}

// ---------------- scan (exclusive prefix of 32 counts -> cursors) ----------------
__global__ void ogtree_scan(const int* __restrict__ cnt, int* __restrict__ cur)
{
    if (threadIdx.x == 0) {
        int acc = 0;
        for (int i = 0; i < 32; ++i) { cur[i] = acc; acc += cnt[i]; }
    }
}

// ---------------- zero counters ----------------
__global__ void ogtree_zero(int* __restrict__ cnt)
{
    if (threadIdx.x < 32) cnt[threadIdx.x] = 0;
}

// ---------------- scatter: compact element ids bucket-contiguously ----------------
#define SC_THREADS 256
__global__ __launch_bounds__(SC_THREADS) void ogtree_scatter(
    const int* __restrict__ idx5a, int* __restrict__ cur, int* __restrict__ ids)
{
    __shared__ int h[32], base[32];
    const int tid = threadIdx.x;
    const int e   = blockIdx.x * SC_THREADS + tid;
    if (tid < 32) h[tid] = 0;
    __syncthreads();
    const int bkt  = idx5a[e] - 31;
    const int rank = atomicAdd(&h[bkt], 1);
    __syncthreads();
    if (tid < 32 && h[tid] > 0) base[tid] = atomicAdd(&cur[tid], h[tid]);
    __syncthreads();
    ids[base[bkt] + rank] = e;
}

// ---------------- Phase 2: levels 5..9 from LDS-staged subtree ----------------
#define P2_THREADS 1024
#define P2_ELEMS   64

__global__ __launch_bounds__(P2_THREADS) void ogtree_p2(
    const float* __restrict__ x, const float* __restrict__ W,
    const float* __restrict__ b, const float* __restrict__ alpha,
    const float* __restrict__ leaves,
    const int* __restrict__ ids, const int* __restrict__ idx5a,
    const float* __restrict__ p5a, float* __restrict__ out)
{
    __shared__ float lsub[31 * NUM_INPUT];    // subtree rows (local heap order)
    __shared__ float la[31], lb_[31];
    __shared__ int   s_n5, s_uni;

    const int tid  = threadIdx.x;
    const int lane = tid & 63, wid = tid >> 6;
    const int g    = lane >> 4, s = lane & 15;
    const int i0   = blockIdx.x * P2_ELEMS;

    const int   id   = ids[i0 + wid * 4 + g];   // 16-lane broadcast load
    const int   myn5 = idx5a[id];
    const float p5v  = p5a[id];

    // x loads early (L3-resident; latency hides under staging)
    const float4* xrow = reinterpret_cast<const float4*>(x + (size_t)id * NUM_INPUT);
    float4 xv0 = xrow[s], xv1 = xrow[16 + s], xv2 = xrow[32 + s], xv3 = xrow[48 + s];

    if (tid == 0) {
        int na = idx5a[ids[i0]];
        int nb = idx5a[ids[i0 + P2_ELEMS - 1]];
        s_n5  = na;
        s_uni = (na == nb);
    }
    __syncthreads();
    const bool uni = (s_uni != 0);
    const int  n5  = s_n5;

    if (uni) {
        // stage the 31-node subtree of n5 (levels 5..9 rows along all paths)
        const float4* Wv = reinterpret_cast<const float4*>(W);
        float4* ls4 = reinterpret_cast<float4*>(lsub);
        #pragma unroll
        for (int i = tid; i < 31 * 64; i += P2_THREADS) {
            int row = i >> 6;
            int col = i & 63;
            int lvl = 31 - __clz(row + 1);
            int gl  = ((n5 + 1) << lvl) - 1 + (row + 1 - (1 << lvl));
            ls4[row * 64 + col] = Wv[(size_t)gl * 64 + col];
        }
        if (tid < 31) {
            int lvl = 31 - __clz(tid + 1);
            int gl  = ((n5 + 1) << lvl) - 1 + (tid + 1 - (1 << lvl));
            la[tid]  = alpha[gl];
            lb_[tid] = b[gl];
        }
    }
    __syncthreads();

    float zn[5];
    int leaf;
    if (uni) {
        int li = 0;   // local heap index within subtree
        #pragma unroll
        for (int d = 0; d < 5; ++d)
            TREE_STEP(lsub, la, lb_, li, zn[d]);
        // li in [31,62] -> global leaf
        leaf = (((n5 + 1) << 5) - 1 + (li - 31)) - N_INTERNAL;
    } else {
        // rare straddle block: global-gather path (identical numerics)
        int idxg = myn5;
        #pragma unroll
        for (int d = 0; d < 5; ++d)
            TREE_STEP(W, alpha, b, idxg, zn[d]);
        leaf = idxg - N_INTERNAL;
    }

    // mult = 1 / (p5 * prod_{levels 5..9} (1 + e^{-|z|}))
    float zsel = -1e30f;
    #pragma unroll
    for (int d = 0; d < 5; ++d)
        zsel = (s == d) ? zn[d] : zsel;
    float f = 1.0f + __expf(zsel);
    float p = group16_reduce_mul(f);
    float mult = 1.0f / (p * p5v);

    const float4 lv = reinterpret_cast<const float4*>(
        leaves + (size_t)leaf * NUM_OUTPUT)[s];
    float4 o;
    o.x = mult * lv.x;
    o.y = mult * lv.y;
    o.z = mult * lv.z;
    o.w = mult * lv.w;
    reinterpret_cast<float4*>(out + (size_t)id * NUM_OUTPUT)[s] = o;
}

// ---------------- monolithic fallback (R8 structure) if ws too small ----------------
#define MONO_THREADS 512
#define MONO_ELEMS   32

__global__ __launch_bounds__(MONO_THREADS) void ogtree_mono(
    const float* __restrict__ x, const float* __restrict__ W,
    const float* __restrict__ b, const float* __restrict__ alpha,
    const float* __restrict__ leaves, float* __restrict__ out)
{
    __shared__ float lds_w[31 * NUM_INPUT];
    __shared__ float la[31], lb_[31];

    const int tid  = threadIdx.x;
    const int lane = tid & 63, wid = tid >> 6;
    const int g    = lane >> 4, s = lane & 15;
    const int elem = blockIdx.x * MONO_ELEMS + wid * 4 + g;

    const float4* xrow = reinterpret_cast<const float4*>(x + (size_t)elem * NUM_INPUT);
    float4 xv0 = xrow[s], xv1 = xrow[16 + s], xv2 = xrow[32 + s], xv3 = xrow[48 + s];

    {
        const float4* Wv = reinterpret_cast<const float4*>(W);
        float4* lw4 = reinterpret_cast<float4*>(lds_w);
        #pragma unroll
        for (int i = tid; i < 31 * 64; i += MONO_THREADS) lw4[i] = Wv[i];
        if (tid < 31) { la[tid] = alpha[tid]; lb_[tid] = b[tid]; }
    }
    __syncthreads();

    int idx = 0;
    float zn[MAX_DEPTH];
    #pragma unroll
    for (int d = 0; d < 5; ++d)
        TREE_STEP(lds_w, la, lb_, idx, zn[d]);
    #pragma unroll
    for (int d = 5; d < MAX_DEPTH; ++d)
        TREE_STEP(W, alpha, b, idx, zn[d]);

    float zsel = -1e30f;
    #pragma unroll
    for (int d = 0; d < MAX_DEPTH; ++d)
        zsel = (s == d) ? zn[d] : zsel;
    float f = 1.0f + __expf(zsel);
    float p = group16_reduce_mul(f);
    float mult = 1.0f / p;

    const int leaf = idx - N_INTERNAL;
    const float4 lv = reinterpret_cast<const float4*>(
        leaves + (size_t)leaf * NUM_OUTPUT)[s];
    float4 o;
    o.x = mult * lv.x;
    o.y = mult * lv.y;
    o.z = mult * lv.z;
    o.w = mult * lv.w;
    reinterpret_cast<float4*>(out + (size_t)elem * NUM_OUTPUT)[s] = o;
}

// ---------------- launch ----------------
extern "C" void kernel_launch(void* const* d_in, const int* in_sizes, int n_in,
                              void* d_out, int out_size, void* d_ws, size_t ws_size,
                              hipStream_t stream) {
    const float* x      = (const float*)d_in[0];
    const float* W      = (const float*)d_in[1];
    const float* b      = (const float*)d_in[2];
    const float* alpha  = (const float*)d_in[3];
    const float* leaves = (const float*)d_in[4];
    float* out = (float*)d_out;

    const int batch = in_sizes[0] / NUM_INPUT;   // 131072

    const size_t need = 64 * sizeof(int) + (size_t)batch * 4 * 3;
    if (ws_size < need) {
        ogtree_mono<<<batch / MONO_ELEMS, MONO_THREADS, 0, stream>>>(
            x, W, b, alpha, leaves, out);
        return;
    }

    int*   cnt   = (int*)d_ws;            // [32]
    int*   cur   = cnt + 32;              // [32]
    int*   idx5a = cnt + 64;              // [batch]
    float* p5a   = (float*)(idx5a + batch);
    int*   ids   = (int*)(p5a + batch);

    ogtree_zero<<<1, 64, 0, stream>>>(cnt);
    ogtree_p1<<<batch / P1_ELEMS, P1_THREADS, 0, stream>>>(
        x, W, b, alpha, cnt, idx5a, p5a);
    ogtree_scan<<<1, 64, 0, stream>>>(cnt, cur);
    ogtree_scatter<<<batch / SC_THREADS, SC_THREADS, 0, stream>>>(idx5a, cur, ids);
    ogtree_p2<<<batch / P2_ELEMS, P2_THREADS, 0, stream>>>(
        x, W, b, alpha, leaves, ids, idx5a, p5a, out);
}

// Round 11
// 47.063 us; speedup vs baseline: 1.9429x; 1.9429x over previous
//
#include <hip/hip_runtime.h>

#define NUM_INPUT   256
#define NUM_OUTPUT  64
#define MAX_DEPTH   10
#define N_INTERNAL  1023
#define STAGED_NODES 31          // tree levels 0..4 staged in LDS (31 KB)
#define THREADS 512              // 8 waves
#define NBLOCKS 1024
#define ELEMS_PER_GROUP 4        // sequential, software-pipelined x prefetch

// Sum-reduce across each 16-lane row using DPP row_ror (VALU pipe, no DS ops).
__device__ __forceinline__ float group16_reduce_add(float acc) {
    int t;
    t = __builtin_amdgcn_update_dpp(0, __float_as_int(acc), 0x121, 0xf, 0xf, true);
    acc += __int_as_float(t);
    t = __builtin_amdgcn_update_dpp(0, __float_as_int(acc), 0x122, 0xf, 0xf, true);
    acc += __int_as_float(t);
    t = __builtin_amdgcn_update_dpp(0, __float_as_int(acc), 0x124, 0xf, 0xf, true);
    acc += __int_as_float(t);
    t = __builtin_amdgcn_update_dpp(0, __float_as_int(acc), 0x128, 0xf, 0xf, true);
    acc += __int_as_float(t);
    return acc;
}

// Product-reduce across each 16-lane row.
__device__ __forceinline__ float group16_reduce_mul(float v) {
    int t;
    t = __builtin_amdgcn_update_dpp(0, __float_as_int(v), 0x121, 0xf, 0xf, true);
    v *= __int_as_float(t);
    t = __builtin_amdgcn_update_dpp(0, __float_as_int(v), 0x122, 0xf, 0xf, true);
    v *= __int_as_float(t);
    t = __builtin_amdgcn_update_dpp(0, __float_as_int(v), 0x124, 0xf, 0xf, true);
    v *= __int_as_float(t);
    t = __builtin_amdgcn_update_dpp(0, __float_as_int(v), 0x128, 0xf, 0xf, true);
    v *= __int_as_float(t);
    return v;
}

// One depth step with explicit x-register set; records -|z| (sigmoid deferred).
#define STEP_X(BASE, IDX, ZND, X0, X1, X2, X3)                              \
    {                                                                       \
        float a_i = lds_a[IDX];                                             \
        float b_i = lds_b[IDX];                                             \
        const float4* wr_ = reinterpret_cast<const float4*>(                \
            (BASE) + (size_t)(IDX) * NUM_INPUT);                            \
        float4 w0 = wr_[s], w1 = wr_[16 + s], w2 = wr_[32 + s], w3 = wr_[48 + s]; \
        float a0 = X0.x * w0.x, a1 = X1.x * w1.x;                           \
        float a2 = X2.x * w2.x, a3 = X3.x * w3.x;                           \
        a0 = fmaf(X0.y, w0.y, a0); a1 = fmaf(X1.y, w1.y, a1);               \
        a2 = fmaf(X2.y, w2.y, a2); a3 = fmaf(X3.y, w3.y, a3);               \
        a0 = fmaf(X0.z, w0.z, a0); a1 = fmaf(X1.z, w1.z, a1);               \
        a2 = fmaf(X2.z, w2.z, a2); a3 = fmaf(X3.z, w3.z, a3);               \
        a0 = fmaf(X0.w, w0.w, a0); a1 = fmaf(X1.w, w1.w, a1);               \
        a2 = fmaf(X2.w, w2.w, a2); a3 = fmaf(X3.w, w3.w, a3);               \
        float acc_ = group16_reduce_add((a0 + a1) + (a2 + a3));             \
        float z = a_i * (acc_ + b_i);                                       \
        ZND = __int_as_float(__float_as_int(z) | 0x80000000);               \
        IDX = 2 * (IDX) + 1 + ((z >= 0.0f) ? 1 : 0);                        \
    }

// Full traversal of one element using x set XC; optionally prefetch the NEXT
// element's x into set XN during this element's deep phase (pinned so the
// compiler cannot sink the loads — R4/R9 showed it otherwise will).
#define ONE_ELEM(E, XC0, XC1, XC2, XC3, XN0, XN1, XN2, XN3, PF)             \
    {                                                                       \
        int idx = 0;                                                        \
        float zn0, zn1, zn2, zn3, zn4, zn5, zn6, zn7, zn8, zn9;             \
        /* depths 0..4 from LDS (DS pipe) */                                \
        STEP_X(lds_w, idx, zn0, XC0, XC1, XC2, XC3)                         \
        STEP_X(lds_w, idx, zn1, XC0, XC1, XC2, XC3)                         \
        STEP_X(lds_w, idx, zn2, XC0, XC1, XC2, XC3)                         \
        STEP_X(lds_w, idx, zn3, XC0, XC1, XC2, XC3)                         \
        STEP_X(lds_w, idx, zn4, XC0, XC1, XC2, XC3)                         \
        if (PF) {                                                           \
            const float4* xp_ = reinterpret_cast<const float4*>(            \
                x + (size_t)(gbase + 4 * ((E) + 1)) * NUM_INPUT);           \
            XN0 = xp_[s];      XN1 = xp_[16 + s];                           \
            XN2 = xp_[32 + s]; XN3 = xp_[48 + s];                           \
            __builtin_amdgcn_sched_barrier(0);                              \
        }                                                                   \
        /* depths 5..9 gathered from global (L2) — covers the prefetch */   \
        STEP_X(W, idx, zn5, XC0, XC1, XC2, XC3)                             \
        STEP_X(W, idx, zn6, XC0, XC1, XC2, XC3)                             \
        STEP_X(W, idx, zn7, XC0, XC1, XC2, XC3)                             \
        STEP_X(W, idx, zn8, XC0, XC1, XC2, XC3)                             \
        STEP_X(W, idx, zn9, XC0, XC1, XC2, XC3)                             \
        /* deferred sigmoid: mult = 1 / prod_d (1 + exp(-|z_d|)) */         \
        float zsel = -1e30f;                                                \
        zsel = (s == 0) ? zn0 : zsel; zsel = (s == 1) ? zn1 : zsel;         \
        zsel = (s == 2) ? zn2 : zsel; zsel = (s == 3) ? zn3 : zsel;         \
        zsel = (s == 4) ? zn4 : zsel; zsel = (s == 5) ? zn5 : zsel;         \
        zsel = (s == 6) ? zn6 : zsel; zsel = (s == 7) ? zn7 : zsel;         \
        zsel = (s == 8) ? zn8 : zsel; zsel = (s == 9) ? zn9 : zsel;         \
        float f = 1.0f + __expf(zsel);                                      \
        float p = group16_reduce_mul(f);                                    \
        float mult = 1.0f / p;                                              \
        const int leaf = idx - N_INTERNAL;                                  \
        const float4 lv = reinterpret_cast<const float4*>(                  \
            leaves + (size_t)leaf * NUM_OUTPUT)[s];                         \
        float4 o;                                                           \
        o.x = mult * lv.x; o.y = mult * lv.y;                               \
        o.z = mult * lv.z; o.w = mult * lv.w;                               \
        reinterpret_cast<float4*>(                                          \
            out + (size_t)(gbase + 4 * (E)) * NUM_OUTPUT)[s] = o;           \
    }

__global__ __launch_bounds__(THREADS, 4) void ogtree_kernel(
    const float* __restrict__ x,
    const float* __restrict__ W,
    const float* __restrict__ b,
    const float* __restrict__ alpha,
    const float* __restrict__ leaves,
    float* __restrict__ out)
{
    __shared__ float lds_w[STAGED_NODES * NUM_INPUT];  // 31 KB
    __shared__ float lds_b[N_INTERNAL];                // 4 KB
    __shared__ float lds_a[N_INTERNAL];                // 4 KB

    const int tid  = threadIdx.x;
    const int lane = tid & 63;
    const int wid  = tid >> 6;
    const int g    = lane >> 4;   // element group within wave (0..3)
    const int s    = lane & 15;   // sub-lane within group
    // group's elements: gbase + 4*e, e = 0..3 (wave reads 4 consecutive
    // elements = contiguous 1KB at each round -> coalesced)
    const int gbase = blockIdx.x * (THREADS / 64) * 16 + wid * 16 + g;

    // ---- element 0's x issued BEFORE staging: latency hides under stage ----
    const float4* xp0 = reinterpret_cast<const float4*>(x + (size_t)gbase * NUM_INPUT);
    float4 xa0 = xp0[s], xa1 = xp0[16 + s], xa2 = xp0[32 + s], xa3 = xp0[48 + s];

    // ---- stage W levels 0..4 (rows 0..30) + all b/alpha ----
    {
        const float4* Wv = reinterpret_cast<const float4*>(W);
        float4* lw4 = reinterpret_cast<float4*>(lds_w);
        #pragma unroll
        for (int i = tid; i < STAGED_NODES * NUM_INPUT / 4; i += THREADS)
            lw4[i] = Wv[i];
        for (int i = tid; i < N_INTERNAL; i += THREADS) {
            lds_b[i] = b[i];
            lds_a[i] = alpha[i];
        }
    }
    __syncthreads();

    float4 xb0, xb1, xb2, xb3;   // ping-pong second x set

    // e=0: current in A, prefetch e=1 into B during deep phase
    ONE_ELEM(0, xa0, xa1, xa2, xa3, xb0, xb1, xb2, xb3, 1)
    // e=1: current in B, prefetch e=2 into A
    ONE_ELEM(1, xb0, xb1, xb2, xb3, xa0, xa1, xa2, xa3, 1)
    // e=2: current in A, prefetch e=3 into B
    ONE_ELEM(2, xa0, xa1, xa2, xa3, xb0, xb1, xb2, xb3, 1)
    // e=3: current in B, no prefetch
    ONE_ELEM(3, xb0, xb1, xb2, xb3, xa0, xa1, xa2, xa3, 0)
}

extern "C" void kernel_launch(void* const* d_in, const int* in_sizes, int n_in,
                              void* d_out, int out_size, void* d_ws, size_t ws_size,
                              hipStream_t stream) {
    const float* x      = (const float*)d_in[0];
    const float* W      = (const float*)d_in[1];
    const float* b      = (const float*)d_in[2];
    const float* alpha  = (const float*)d_in[3];
    const float* leaves = (const float*)d_in[4];
    float* out = (float*)d_out;

    // 1024 blocks * 8 waves * 4 groups * 4 elems = 131072
    ogtree_kernel<<<NBLOCKS, THREADS, 0, stream>>>(x, W, b, alpha, leaves, out);
}